// Round 14
// baseline (146.205 us; speedup 1.0000x reference)
//
#include <hip/hip_runtime.h>
#include <hip/hip_fp16.h>

// Problem: B=2, H=8, L=2048, D=64.
// out0 = masked(p + p^T) @ v   (B,H,L,D)
// out1 = p + p^T               (B,H,L,L)
// p[b,h,qi,ki] += exp(-(q_sorted_r - k_sorted_r)^2)/D for rank-matched sorted
// q/k along L per (b,h,d). Each attn row receives exactly 64 direct + 64
// transpose entries (one per d) -> collision-free 4B slot per entry in the
// first 512B of each row's dense output region (u16 col | fp16 weight).
//
// R14: VALU butterfly exchanges, bug-pinned by the R12/R13 failure pair:
//  - m=4: banks 0,2 need src[i+4] -> row_shl:4 (0x104); banks 1,3 need
//    src[i-4] -> row_shr:4 (0x114).  (R12 ror-pair and R13 assignment were
//    each inverted one way; this is the unique survivor of the 2x2 grid.)
//  - m=16/32: __builtin_amdgcn_permlane{16,32}_swap(x,x): res.x=a (vdst),
//    res.y=b (vsrc); partner = (lid&M) ? a : b  (R12's select was correct).
//  - m=8: row_ror:8 (xor-symmetric, convention-independent). m=1,2:
//    quad_perm (verified in passing R11).

#define LSEQ 2048
#define DDIM 64
#define NBH  16
#define NTHR 256
#define EPT  8   // elements per thread in sort

typedef float    f32x4 __attribute__((ext_vector_type(4)));
typedef unsigned u32x2 __attribute__((ext_vector_type(2)));

#define LGKM0() asm volatile("s_waitcnt lgkmcnt(0)" ::: "memory")

__device__ __forceinline__ unsigned long long pack_kv(float f, unsigned idx) {
  unsigned u = __float_as_uint(f);
  u = (u & 0x80000000u) ? ~u : (u | 0x80000000u);   // sortable-ascending
  return ((unsigned long long)u << 32) | idx;
}

__device__ __forceinline__ float unpack_val(unsigned long long p) {
  unsigned us = (unsigned)(p >> 32);
  unsigned u = (us & 0x80000000u) ? (us & 0x7fffffffu) : ~us;
  return __uint_as_float(u);
}

// partner value of x under lane-xor M, all on VALU (no DS pipe).
template<int M>
__device__ __forceinline__ unsigned xchg32(unsigned x, int lid) {
  if constexpr (M == 1) {        // quad_perm [1,0,3,2]
    return (unsigned)__builtin_amdgcn_update_dpp(0, (int)x, 0xB1, 0xF, 0xF, true);
  } else if constexpr (M == 2) { // quad_perm [2,3,0,1]
    return (unsigned)__builtin_amdgcn_update_dpp(0, (int)x, 0x4E, 0xF, 0xF, true);
  } else if constexpr (M == 4) {
    // banks 0,2 (pos&4==0): partner src[i+4] -> row_shl:4 (0x104)
    // banks 1,3 (pos&4==4): partner src[i-4] -> row_shr:4 (0x114)
    int r = __builtin_amdgcn_update_dpp((int)x, (int)x, 0x104, 0xF, 0x5, false);
    r     = __builtin_amdgcn_update_dpp(r,      (int)x, 0x114, 0xF, 0xA, false);
    return (unsigned)r;
  } else if constexpr (M == 8) { // xor-8 = row_ror:8 (+8 == -8 mod 16)
    return (unsigned)__builtin_amdgcn_update_dpp(0, (int)x, 0x128, 0xF, 0xF, true);
  } else if constexpr (M == 16) {
#if __has_builtin(__builtin_amdgcn_permlane16_swap)
    // a.row1<->b.row0, a.row3<->b.row2: a[16..31]=x[0..15], b[0..15]=x[16..31]
    u32x2 r = __builtin_amdgcn_permlane16_swap(x, x, false, false);
    return (lid & 16) ? r.x : r.y;   // r.x = a (vdst), r.y = b (vsrc)
#else
    return __shfl_xor(x, 16);
#endif
  } else {                       // M == 32
#if __has_builtin(__builtin_amdgcn_permlane32_swap)
    // a[32..63]=x[0..31], b[0..31]=x[32..63]
    u32x2 r = __builtin_amdgcn_permlane32_swap(x, x, false, false);
    return (lid & 32) ? r.x : r.y;
#else
    return __shfl_xor(x, 32);
#endif
  }
}

template<int M>
__device__ __forceinline__ unsigned long long xchg64(unsigned long long x, int lid) {
  unsigned lo = xchg32<M>((unsigned)x, lid);
  unsigned hi = xchg32<M>((unsigned)(x >> 32), lid);
  return ((unsigned long long)hi << 32) | lo;
}

// ---- fused prep: blocks [0,512) transpose q,k -> [bh][D][L];
//      blocks [512, 512+4096) pack mask int32 -> bit mask u64[2048][32]
__global__ __launch_bounds__(256) void prep_kernel(
    const float* __restrict__ q, const float* __restrict__ k,
    float* __restrict__ qT, float* __restrict__ kT,
    const int* __restrict__ mask, unsigned long long* __restrict__ mbits) {
  const int t = threadIdx.x;
  if (blockIdx.x < 512) {
    __shared__ float tq[64][65], tk[64][65];
    const int bh = blockIdx.x >> 5, chunk = blockIdx.x & 31;
    const size_t ib = (size_t)bh * LSEQ * DDIM + (size_t)chunk * 64 * DDIM;
    #pragma unroll
    for (int s = 0; s < 16; ++s) {
      int i = t + s * 256;              // 64(l) x 64(d) tile
      int l = i >> 6, d = i & 63;
      tq[l][d] = q[ib + i];
      tk[l][d] = k[ib + i];
    }
    __syncthreads();
    const size_t ob = (size_t)bh * DDIM * LSEQ + (size_t)chunk * 64;
    #pragma unroll
    for (int s = 0; s < 16; ++s) {
      int o = t + s * 256;
      int d = o >> 6, l = o & 63;
      qT[ob + (size_t)d * LSEQ + l] = tq[l][d];
      kT[ob + (size_t)d * LSEQ + l] = tk[l][d];
    }
  } else {
    const int w = (blockIdx.x - 512) * 4 + (t >> 6);  // u64 word id
    const int lane = t & 63;
    unsigned long long b = __ballot(mask[(size_t)w * 64 + lane] != 0);
    if (lane == 0) mbits[w] = b;
  }
}

#define CSWP(a, x, y, up) \
  { if ((a[x] > a[y]) == (up)) { auto _t = a[x]; a[x] = a[y]; a[y] = _t; } }

// full bitonic sort of 8 contiguous elems (base index 8t); u8 = dir for kk=8
__device__ __forceinline__ void sort8(unsigned long long* a, bool u8) {
  CSWP(a,0,1,true);  CSWP(a,2,3,false); CSWP(a,4,5,true);  CSWP(a,6,7,false);
  CSWP(a,0,2,true);  CSWP(a,1,3,true);  CSWP(a,4,6,false); CSWP(a,5,7,false);
  CSWP(a,0,1,true);  CSWP(a,2,3,true);  CSWP(a,4,5,false); CSWP(a,6,7,false);
  CSWP(a,0,4,u8); CSWP(a,1,5,u8); CSWP(a,2,6,u8); CSWP(a,3,7,u8);
  CSWP(a,0,2,u8); CSWP(a,1,3,u8); CSWP(a,4,6,u8); CSWP(a,5,7,u8);
  CSWP(a,0,1,u8); CSWP(a,2,3,u8); CSWP(a,4,5,u8); CSWP(a,6,7,u8);
}

// bitonic merge j=4,2,1 over 8 contiguous elems, uniform direction
__device__ __forceinline__ void merge8(unsigned long long* a, bool up) {
  CSWP(a,0,4,up); CSWP(a,1,5,up); CSWP(a,2,6,up); CSWP(a,3,7,up);
  CSWP(a,0,2,up); CSWP(a,1,3,up); CSWP(a,4,6,up); CSWP(a,5,7,up);
  CSWP(a,0,1,up); CSWP(a,2,3,up); CSWP(a,4,5,up); CSWP(a,6,7,up);
}

__device__ __forceinline__ unsigned long long bmin(unsigned long long a, unsigned long long b) {
  return a < b ? a : b;
}
__device__ __forceinline__ unsigned long long bmax(unsigned long long a, unsigned long long b) {
  return a > b ? a : b;
}

#define STAGE(M) { \
    const bool ks = (((t & (M)) == 0) == up); \
    _Pragma("unroll") \
    for (int p = 0; p < EPT; ++p) { \
      unsigned long long aq = xchg64<M>(rq[p], lid); \
      unsigned long long ak = xchg64<M>(rk[p], lid); \
      rq[p] = ks ? bmin(rq[p], aq) : bmax(rq[p], aq); \
      rk[p] = ks ? bmin(rk[p], ak) : bmax(rk[p], ak); \
    } }

// One block per (b,h,d): sort q-slice & k-slice, rank-match, scatter entries.
// Thread t owns elements [8t, 8t+8). Stages j<=4: in-register merge8.
// Stages j=8..256 (m=1..32): VALU exchange (DPP / permlane_swap).
// Stages j=512,1024: cross-wave -> one shared 16KB buffer, two passes.
__global__ __launch_bounds__(NTHR, 4) void sort_emit_kernel(
    const float* __restrict__ qsrc, const float* __restrict__ ksrc,
    int stride, float* __restrict__ attn) {
  __shared__ unsigned long long sx[EPT][NTHR];   // 16 KB
  const int bid = blockIdx.x;
  const int lb  = (bid & 7) * (NBH * DDIM / 8) + (bid >> 3);  // XCD chunking
  const int bh = lb >> 6, d = lb & 63;
  const int t = threadIdx.x;
  const int lid = t & 63;

  unsigned long long rq[EPT], rk[EPT];
  if (stride == 1) {
    const float* qp = qsrc + ((size_t)bh * DDIM + d) * LSEQ;
    const float* kp = ksrc + ((size_t)bh * DDIM + d) * LSEQ;
    f32x4 a0 = ((const f32x4*)qp)[2*t], a1 = ((const f32x4*)qp)[2*t+1];
    f32x4 b0 = ((const f32x4*)kp)[2*t], b1 = ((const f32x4*)kp)[2*t+1];
    float qa[8] = {a0.x,a0.y,a0.z,a0.w,a1.x,a1.y,a1.z,a1.w};
    float ka[8] = {b0.x,b0.y,b0.z,b0.w,b1.x,b1.y,b1.z,b1.w};
    #pragma unroll
    for (int p = 0; p < 8; ++p) {
      rq[p] = pack_kv(qa[p], 8*t + p);
      rk[p] = pack_kv(ka[p], 8*t + p);
    }
  } else {
    const size_t base = (size_t)bh * LSEQ * DDIM + d;
    #pragma unroll
    for (int p = 0; p < 8; ++p) {
      int l = 8*t + p;
      rq[p] = pack_kv(qsrc[base + (size_t)l * DDIM], l);
      rk[p] = pack_kv(ksrc[base + (size_t)l * DDIM], l);
    }
  }

  sort8(rq, (t & 1) == 0);
  sort8(rk, (t & 1) == 0);

  for (int kk = 16; kk <= LSEQ; kk <<= 1) {
    const bool up = (((8 * t) & kk) == 0);
    // LDS stages: j >= 512 (partner thread in another wave); two passes
    for (int j = kk >> 1; j >= 512; j >>= 1) {
      const int m = j >> 3;
      const int pt = t ^ m;
      const bool ks = (((t & m) == 0) == up);
      __syncthreads();
      #pragma unroll
      for (int p = 0; p < EPT; ++p) sx[p][t] = rq[p];
      __syncthreads();
      #pragma unroll
      for (int p = 0; p < EPT; ++p) {
        unsigned long long aq = sx[p][pt];
        rq[p] = ks ? bmin(rq[p], aq) : bmax(rq[p], aq);
      }
      __syncthreads();
      #pragma unroll
      for (int p = 0; p < EPT; ++p) sx[p][t] = rk[p];
      __syncthreads();
      #pragma unroll
      for (int p = 0; p < EPT; ++p) {
        unsigned long long ak = sx[p][pt];
        rk[p] = ks ? bmin(rk[p], ak) : bmax(rk[p], ak);
      }
    }
    // within-wave stages, all VALU: j = min(kk/2, 256) .. 8  (m = j/8)
    if (kk >= 512) STAGE(32);
    if (kk >= 256) STAGE(16);
    if (kk >= 128) STAGE(8);
    if (kk >= 64)  STAGE(4);
    if (kk >= 32)  STAGE(2);
    STAGE(1);
    merge8(rq, up);
    merge8(rk, up);
  }

  // emit from registers; rank r = 8t+p, final order ascending.
  // entry = u16 col | fp16 weight  (4B; w <= 1/64, fp16 rel err 2^-11)
  // PLAIN stores: scatter relies on L2 write-combining (R10 lesson).
  float* abh = attn + (size_t)bh * LSEQ * LSEQ;
  #pragma unroll
  for (int p = 0; p < 8; ++p) {
    unsigned qi = (unsigned)(rq[p] & 0xffffffffu);
    unsigned ki = (unsigned)(rk[p] & 0xffffffffu);
    float qv = unpack_val(rq[p]);
    float kv = unpack_val(rk[p]);
    float diff = qv - kv;
    float w = expf(-diff * diff) * (1.0f / (float)DDIM);
    unsigned hw = (unsigned)__half_as_ushort(__float2half(w));
    ((unsigned*)(abh + (size_t)qi * LSEQ))[d]      = ki | (hw << 16);  // slot d
    ((unsigned*)(abh + (size_t)ki * LSEQ))[64 + d] = qi | (hw << 16);  // slot 64+d
  }
}

__device__ __forceinline__ float half_bits_to_f32(unsigned bits) {
  return __half2float(__ushort_as_half((unsigned short)bits));
}

// One WAVE per attn row (128-thr blocks = 2 independent waves, NO
// __syncthreads -- all LDS state is per-wave, ordered by wave-local lgkmcnt).
// Phase order: entry load -> mask compaction -> matvec (loads only) -> out
// store -> densify + NT dense-row stores LAST (so no v-load ever waits behind
// an outstanding store in the vmcnt FIFO).
template<bool BITS>
__global__ __launch_bounds__(128) void row_kernel(
    float* __restrict__ attn, const float* __restrict__ v,
    const int* __restrict__ mask, const unsigned long long* __restrict__ mbits,
    float* __restrict__ out) {
  __shared__ float rowbuf[2][1024];
  __shared__ unsigned cent[2][136];              // compacted active entries
  __shared__ unsigned long long mb[2][32];
  const int wv = threadIdx.x >> 6, lane = threadIdx.x & 63;
  const int bid = blockIdx.x;
  const int lb = (bid & 7) * ((NBH * LSEQ / 2) / 8) + (bid >> 3);  // XCD chunking
  const int R = lb * 2 + wv;
  const int bh = R >> 11, r = R & (LSEQ - 1);
  float* arow = attn + (size_t)R * LSEQ;

  // phase 1: loads. Entry list = first 512B of this row's dense region.
  u32x2 ep = __builtin_nontemporal_load(((const u32x2*)arow) + lane);
  if (BITS && lane < 32) mb[wv][lane] = mbits[(size_t)r * 32 + lane];

  // phase 2: active tests + ballot compaction (lane holds entries 2l, 2l+1)
  const unsigned cA = ep.x & 0xFFFFu, cB = ep.y & 0xFFFFu;
  bool aA, aB;
  if (BITS) {
    LGKM0();
    aA = !((mb[wv][cA >> 6] >> (cA & 63)) & 1ull);
    aB = !((mb[wv][cB >> 6] >> (cB & 63)) & 1ull);
  } else {
    const int* mrow = mask + (size_t)r * LSEQ;
    aA = (mrow[cA] == 0);
    aB = (mrow[cB] == 0);
  }
  unsigned long long m0 = __ballot(aA), m1 = __ballot(aB);
  int n0 = __popcll(m0);
  int n  = n0 + __popcll(m1);
  if (aA) cent[wv][__popcll(m0 & ((1ull << lane) - 1ull))] = ep.x;
  if (aB) cent[wv][n0 + __popcll(m1 & ((1ull << lane) - 1ull))] = ep.y;
  int npad = (n + 7) & ~7;
  if (lane < npad - n) cent[wv][n + lane] = 0u;   // col 0, w = 0
  LGKM0();

  // phase 3: matvec over active entries only (pure loads, 8 accumulators)
  const float* vb = v + (size_t)bh * LSEQ * DDIM;
  float acc[8];
  #pragma unroll
  for (int u = 0; u < 8; ++u) acc[u] = 0.0f;
  for (int e = 0; e < npad; e += 8) {
    #pragma unroll
    for (int u = 0; u < 8; ++u) {
      unsigned en = cent[wv][e + u];
      acc[u] += half_bits_to_f32(en >> 16) * vb[(size_t)(en & 0xFFFFu) * DDIM + lane];
    }
  }
  float s = ((acc[0] + acc[1]) + (acc[2] + acc[3])) +
            ((acc[4] + acc[5]) + (acc[6] + acc[7]));
  out[(size_t)R * DDIM + lane] = s;

  // phase 4: densify + dense-row NT stores (LAST; nothing waits on them)
  const float wA = half_bits_to_f32(ep.x >> 16);
  const float wB = half_bits_to_f32(ep.y >> 16);
  #pragma unroll
  for (int h = 0; h < 2; ++h) {
    f32x4 z = {0.0f, 0.0f, 0.0f, 0.0f};
    #pragma unroll
    for (int i = 0; i < 4; ++i) ((f32x4*)rowbuf[wv])[i * 64 + lane] = z;
    LGKM0();
    if ((int)(cA >> 10) == h) atomicAdd(&rowbuf[wv][cA & 1023], wA);
    if ((int)(cB >> 10) == h) atomicAdd(&rowbuf[wv][cB & 1023], wB);
    LGKM0();
    #pragma unroll
    for (int i = 0; i < 4; ++i) {
      f32x4 val = ((const f32x4*)rowbuf[wv])[i * 64 + lane];
      __builtin_nontemporal_store(val, ((f32x4*)(arow + (h << 10))) + i * 64 + lane);
    }
    LGKM0();   // rowbuf reads drained before next-half zeroing
  }
}

extern "C" void kernel_launch(void* const* d_in, const int* in_sizes, int n_in,
                              void* d_out, int out_size, void* d_ws, size_t ws_size,
                              hipStream_t stream) {
  const float* q = (const float*)d_in[0];
  const float* k = (const float*)d_in[1];
  const float* v = (const float*)d_in[2];
  const int* mask = (const int*)d_in[3];
  float* out = (float*)d_out;
  float* attn = out + (size_t)NBH * LSEQ * DDIM;

  const size_t qk_elems = (size_t)NBH * DDIM * LSEQ;        // 2M floats each
  const size_t qk_bytes = 2 * qk_elems * sizeof(float);     // 16 MiB
  const size_t mb_bytes = (size_t)LSEQ * (LSEQ / 64) * 8;   // 512 KiB
  const bool has_full = ws_size >= qk_bytes + mb_bytes;

  float* qT = (float*)d_ws;
  float* kT = qT + qk_elems;
  unsigned long long* mbits = (unsigned long long*)(kT + qk_elems);

  if (has_full) {
    prep_kernel<<<512 + (LSEQ * (LSEQ / 64)) / 4, 256, 0, stream>>>(
        q, k, qT, kT, mask, mbits);
    sort_emit_kernel<<<NBH * DDIM, NTHR, 0, stream>>>(qT, kT, 1, attn);
    row_kernel<true><<<(NBH * LSEQ) / 2, 128, 0, stream>>>(attn, v, nullptr, mbits, out);
  } else {
    sort_emit_kernel<<<NBH * DDIM, NTHR, 0, stream>>>(q, k, DDIM, attn);
    row_kernel<false><<<(NBH * LSEQ) / 2, 128, 0, stream>>>(attn, v, mask, nullptr, out);
  }
}

// Round 16
// 134.634 us; speedup vs baseline: 1.0859x; 1.0859x over previous
//
#include <hip/hip_runtime.h>
#include <hip/hip_fp16.h>

// Problem: B=2, H=8, L=2048, D=64.
// out0 = masked(p + p^T) @ v   (B,H,L,D)
// out1 = p + p^T               (B,H,L,L)
// p[b,h,qi,ki] += exp(-(q_sorted_r - k_sorted_r)^2)/D for rank-matched sorted
// q/k along L per (b,h,d). Each attn row receives exactly 64 direct + 64
// transpose entries (one per d) -> collision-free 4B slot per entry in the
// first 512B of each row's dense output region (u16 col | fp16 weight).
//
// R16 = R11 (best passing: 137.9us, u64 keys -- R15 proved exact-order keys
// are required) with the sort restructured as SPLIT HALVES: 512-thr blocks,
// threads 0-255 sort q, 256-511 sort k (same network each). Halves per-wave
// chain length + register state; LDS stages 1-pass (6 barriers vs 12); emit
// balances scatter stores across halves via a 32KB LDS rank exchange.

#define LSEQ 2048
#define DDIM 64
#define NBH  16
#define SNTHR 512
#define EPT  8   // elements per thread (per half) in sort

typedef float    f32x4 __attribute__((ext_vector_type(4)));
typedef unsigned u32x2 __attribute__((ext_vector_type(2)));

#define LGKM0() asm volatile("s_waitcnt lgkmcnt(0)" ::: "memory")

__device__ __forceinline__ unsigned long long pack_kv(float f, unsigned idx) {
  unsigned u = __float_as_uint(f);
  u = (u & 0x80000000u) ? ~u : (u | 0x80000000u);   // sortable-ascending
  return ((unsigned long long)u << 32) | idx;
}

__device__ __forceinline__ float unpack_val(unsigned long long p) {
  unsigned us = (unsigned)(p >> 32);
  unsigned u = (us & 0x80000000u) ? (us & 0x7fffffffu) : ~us;
  return __uint_as_float(u);
}

// lane-xor-1 / lane-xor-2 exchange via DPP quad_perm (VALU, no DS pipe).
// 0xB1 = quad_perm [1,0,3,2] (xor 1); 0x4E = quad_perm [2,3,0,1] (xor 2).
template<int CTRL>
__device__ __forceinline__ unsigned long long dpp_swap(unsigned long long x) {
  int lo = __builtin_amdgcn_update_dpp(0, (int)(unsigned)x,         CTRL, 0xF, 0xF, true);
  int hi = __builtin_amdgcn_update_dpp(0, (int)(unsigned)(x >> 32), CTRL, 0xF, 0xF, true);
  return ((unsigned long long)(unsigned)hi << 32) | (unsigned)lo;
}

// ---- fused prep: blocks [0,512) transpose q,k -> [bh][D][L];
//      blocks [512, 512+4096) pack mask int32 -> bit mask u64[2048][32]
__global__ __launch_bounds__(256) void prep_kernel(
    const float* __restrict__ q, const float* __restrict__ k,
    float* __restrict__ qT, float* __restrict__ kT,
    const int* __restrict__ mask, unsigned long long* __restrict__ mbits) {
  const int t = threadIdx.x;
  if (blockIdx.x < 512) {
    __shared__ float tq[64][65], tk[64][65];
    const int bh = blockIdx.x >> 5, chunk = blockIdx.x & 31;
    const size_t ib = (size_t)bh * LSEQ * DDIM + (size_t)chunk * 64 * DDIM;
    #pragma unroll
    for (int s = 0; s < 16; ++s) {
      int i = t + s * 256;              // 64(l) x 64(d) tile
      int l = i >> 6, d = i & 63;
      tq[l][d] = q[ib + i];
      tk[l][d] = k[ib + i];
    }
    __syncthreads();
    const size_t ob = (size_t)bh * DDIM * LSEQ + (size_t)chunk * 64;
    #pragma unroll
    for (int s = 0; s < 16; ++s) {
      int o = t + s * 256;
      int d = o >> 6, l = o & 63;
      qT[ob + (size_t)d * LSEQ + l] = tq[l][d];
      kT[ob + (size_t)d * LSEQ + l] = tk[l][d];
    }
  } else {
    const int w = (blockIdx.x - 512) * 4 + (t >> 6);  // u64 word id
    const int lane = t & 63;
    unsigned long long b = __ballot(mask[(size_t)w * 64 + lane] != 0);
    if (lane == 0) mbits[w] = b;
  }
}

#define CSWP(a, x, y, up) \
  { if ((a[x] > a[y]) == (up)) { auto _t = a[x]; a[x] = a[y]; a[y] = _t; } }

// full bitonic sort of 8 contiguous elems (base index 8*tt); u8 = dir for kk=8
__device__ __forceinline__ void sort8(unsigned long long* a, bool u8) {
  CSWP(a,0,1,true);  CSWP(a,2,3,false); CSWP(a,4,5,true);  CSWP(a,6,7,false);
  CSWP(a,0,2,true);  CSWP(a,1,3,true);  CSWP(a,4,6,false); CSWP(a,5,7,false);
  CSWP(a,0,1,true);  CSWP(a,2,3,true);  CSWP(a,4,5,false); CSWP(a,6,7,false);
  CSWP(a,0,4,u8); CSWP(a,1,5,u8); CSWP(a,2,6,u8); CSWP(a,3,7,u8);
  CSWP(a,0,2,u8); CSWP(a,1,3,u8); CSWP(a,4,6,u8); CSWP(a,5,7,u8);
  CSWP(a,0,1,u8); CSWP(a,2,3,u8); CSWP(a,4,5,u8); CSWP(a,6,7,u8);
}

// bitonic merge j=4,2,1 over 8 contiguous elems, uniform direction
__device__ __forceinline__ void merge8(unsigned long long* a, bool up) {
  CSWP(a,0,4,up); CSWP(a,1,5,up); CSWP(a,2,6,up); CSWP(a,3,7,up);
  CSWP(a,0,2,up); CSWP(a,1,3,up); CSWP(a,4,6,up); CSWP(a,5,7,up);
  CSWP(a,0,1,up); CSWP(a,2,3,up); CSWP(a,4,5,up); CSWP(a,6,7,up);
}

__device__ __forceinline__ unsigned long long bmin(unsigned long long a, unsigned long long b) {
  return a < b ? a : b;
}
__device__ __forceinline__ unsigned long long bmax(unsigned long long a, unsigned long long b) {
  return a > b ? a : b;
}

// One 512-thr block per (b,h,d). Threads 0-255 (half 0) sort the q-slice,
// threads 256-511 (half 1) sort the k-slice -- identical 2048-elem bitonic
// network per half (tt = t & 255, EPT=8). Stages j<=4: in-register merge8.
// j=8 (m=1), j=16 (m=2): DPP quad_perm. j=32..256 (m=4..32): __shfl_xor.
// j=512,1024: cross-thread via per-half 16KB LDS, ONE pass per stage.
// Emit: both halves publish sorted keys in LDS, each half reads the other's
// rank-partner and issues its own entry type (8 scatter stores/thread).
__global__ __launch_bounds__(SNTHR) void sort_emit_kernel(
    const float* __restrict__ qsrc, const float* __restrict__ ksrc,
    int stride, float* __restrict__ attn) {
  __shared__ unsigned long long sx[2][EPT][256];   // 32 KB
  const int bid = blockIdx.x;
  const int lb  = (bid & 7) * (NBH * DDIM / 8) + (bid >> 3);  // XCD chunking
  const int bh = lb >> 6, d = lb & 63;
  const int t = threadIdx.x;
  const int half = t >> 8;          // 0 = q, 1 = k
  const int tt = t & 255;           // position within the half's network

  unsigned long long rr[EPT];
  if (stride == 1) {
    const float* sp = (half ? ksrc : qsrc) + ((size_t)bh * DDIM + d) * LSEQ;
    f32x4 a0 = ((const f32x4*)sp)[2*tt], a1 = ((const f32x4*)sp)[2*tt+1];
    float va[8] = {a0.x,a0.y,a0.z,a0.w,a1.x,a1.y,a1.z,a1.w};
    #pragma unroll
    for (int p = 0; p < 8; ++p) rr[p] = pack_kv(va[p], 8*tt + p);
  } else {
    const float* sp = half ? ksrc : qsrc;
    const size_t base = (size_t)bh * LSEQ * DDIM + d;
    #pragma unroll
    for (int p = 0; p < 8; ++p) {
      int l = 8*tt + p;
      rr[p] = pack_kv(sp[base + (size_t)l * DDIM], l);
    }
  }

  sort8(rr, (tt & 1) == 0);

  for (int kk = 16; kk <= LSEQ; kk <<= 1) {
    const bool up = (((8 * tt) & kk) == 0);
    // LDS stages: j >= 512 (partner thread in another wave); one pass,
    // both halves exchange simultaneously in their own 16KB region.
    for (int j = kk >> 1; j >= 512; j >>= 1) {
      const int m = j >> 3;
      const int pt = tt ^ m;
      const bool ks = (((tt & m) == 0) == up);
      __syncthreads();
      #pragma unroll
      for (int p = 0; p < EPT; ++p) sx[half][p][tt] = rr[p];
      __syncthreads();
      #pragma unroll
      for (int p = 0; p < EPT; ++p) {
        unsigned long long a = sx[half][p][pt];
        rr[p] = ks ? bmin(rr[p], a) : bmax(rr[p], a);
      }
    }
    // shfl stages: 32 <= j <= 256 (m = j/8 in 4..32) on the DS pipe
    const int jstart = (kk >> 1) < 256 ? (kk >> 1) : 256;
    for (int j = jstart; j >= 32; j >>= 1) {
      const int m = j >> 3;
      const bool ks = (((tt & m) == 0) == up);
      #pragma unroll
      for (int p = 0; p < EPT; ++p) {
        unsigned long long a = __shfl_xor(rr[p], m);
        rr[p] = ks ? bmin(rr[p], a) : bmax(rr[p], a);
      }
    }
    // m=2 stage (j=16) via DPP quad_perm [2,3,0,1]
    if (kk >= 32) {
      const bool ks = (((tt & 2) == 0) == up);
      #pragma unroll
      for (int p = 0; p < EPT; ++p) {
        unsigned long long a = dpp_swap<0x4E>(rr[p]);
        rr[p] = ks ? bmin(rr[p], a) : bmax(rr[p], a);
      }
    }
    // m=1 stage (j=8) via DPP quad_perm [1,0,3,2]
    {
      const bool ks = (((tt & 1) == 0) == up);
      #pragma unroll
      for (int p = 0; p < EPT; ++p) {
        unsigned long long a = dpp_swap<0xB1>(rr[p]);
        rr[p] = ks ? bmin(rr[p], a) : bmax(rr[p], a);
      }
    }
    merge8(rr, up);
  }

  // publish sorted keys; each half reads the other's rank-partner and emits
  // its own entry type. rank r = 8*tt+p, ascending order in each half.
  // entry = u16 col | fp16 weight. PLAIN stores (R10: NT scatter is poison).
  __syncthreads();
  #pragma unroll
  for (int p = 0; p < EPT; ++p) sx[half][p][tt] = rr[p];
  __syncthreads();
  float* abh = attn + (size_t)bh * LSEQ * LSEQ;
  #pragma unroll
  for (int p = 0; p < EPT; ++p) {
    unsigned long long mine  = rr[p];
    unsigned long long other = sx[half ^ 1][p][tt];
    unsigned mi = (unsigned)(mine  & 0xffffffffu);
    unsigned oi = (unsigned)(other & 0xffffffffu);
    float mv = unpack_val(mine), ov = unpack_val(other);
    float diff = mv - ov;
    float w = expf(-diff * diff) * (1.0f / (float)DDIM);
    unsigned hw = (unsigned)__half_as_ushort(__float2half(w));
    // half 0 (mine=q): direct entry, row qi, slot d.
    // half 1 (mine=k): transpose entry, row ki, slot 64+d.
    ((unsigned*)(abh + (size_t)mi * LSEQ))[(half << 6) + d] = oi | (hw << 16);
  }
}

__device__ __forceinline__ float half_bits_to_f32(unsigned bits) {
  return __half2float(__ushort_as_half((unsigned short)bits));
}

// One WAVE per attn row (128-thr blocks = 2 independent waves, NO
// __syncthreads -- all LDS state is per-wave, ordered by wave-local lgkmcnt).
// Phase order: entry load -> mask compaction -> matvec (loads only) -> out
// store -> densify + NT dense-row stores LAST (so no v-load ever waits behind
// an outstanding store in the vmcnt FIFO).
template<bool BITS>
__global__ __launch_bounds__(128) void row_kernel(
    float* __restrict__ attn, const float* __restrict__ v,
    const int* __restrict__ mask, const unsigned long long* __restrict__ mbits,
    float* __restrict__ out) {
  __shared__ float rowbuf[2][1024];
  __shared__ unsigned cent[2][136];              // compacted active entries
  __shared__ unsigned long long mb[2][32];
  const int wv = threadIdx.x >> 6, lane = threadIdx.x & 63;
  const int bid = blockIdx.x;
  const int lb = (bid & 7) * ((NBH * LSEQ / 2) / 8) + (bid >> 3);  // XCD chunking
  const int R = lb * 2 + wv;
  const int bh = R >> 11, r = R & (LSEQ - 1);
  float* arow = attn + (size_t)R * LSEQ;

  // phase 1: loads. Entry list = first 512B of this row's dense region.
  u32x2 ep = __builtin_nontemporal_load(((const u32x2*)arow) + lane);
  if (BITS && lane < 32) mb[wv][lane] = mbits[(size_t)r * 32 + lane];

  // phase 2: active tests + ballot compaction (lane holds entries 2l, 2l+1)
  const unsigned cA = ep.x & 0xFFFFu, cB = ep.y & 0xFFFFu;
  bool aA, aB;
  if (BITS) {
    LGKM0();
    aA = !((mb[wv][cA >> 6] >> (cA & 63)) & 1ull);
    aB = !((mb[wv][cB >> 6] >> (cB & 63)) & 1ull);
  } else {
    const int* mrow = mask + (size_t)r * LSEQ;
    aA = (mrow[cA] == 0);
    aB = (mrow[cB] == 0);
  }
  unsigned long long m0 = __ballot(aA), m1 = __ballot(aB);
  int n0 = __popcll(m0);
  int n  = n0 + __popcll(m1);
  if (aA) cent[wv][__popcll(m0 & ((1ull << lane) - 1ull))] = ep.x;
  if (aB) cent[wv][n0 + __popcll(m1 & ((1ull << lane) - 1ull))] = ep.y;
  int npad = (n + 7) & ~7;
  if (lane < npad - n) cent[wv][n + lane] = 0u;   // col 0, w = 0
  LGKM0();

  // phase 3: matvec over active entries only (pure loads, 8 accumulators)
  const float* vb = v + (size_t)bh * LSEQ * DDIM;
  float acc[8];
  #pragma unroll
  for (int u = 0; u < 8; ++u) acc[u] = 0.0f;
  for (int e = 0; e < npad; e += 8) {
    #pragma unroll
    for (int u = 0; u < 8; ++u) {
      unsigned en = cent[wv][e + u];
      acc[u] += half_bits_to_f32(en >> 16) * vb[(size_t)(en & 0xFFFFu) * DDIM + lane];
    }
  }
  float s = ((acc[0] + acc[1]) + (acc[2] + acc[3])) +
            ((acc[4] + acc[5]) + (acc[6] + acc[7]));
  out[(size_t)R * DDIM + lane] = s;

  // phase 4: densify + dense-row NT stores (LAST; nothing waits on them)
  const float wA = half_bits_to_f32(ep.x >> 16);
  const float wB = half_bits_to_f32(ep.y >> 16);
  #pragma unroll
  for (int h = 0; h < 2; ++h) {
    f32x4 z = {0.0f, 0.0f, 0.0f, 0.0f};
    #pragma unroll
    for (int i = 0; i < 4; ++i) ((f32x4*)rowbuf[wv])[i * 64 + lane] = z;
    LGKM0();
    if ((int)(cA >> 10) == h) atomicAdd(&rowbuf[wv][cA & 1023], wA);
    if ((int)(cB >> 10) == h) atomicAdd(&rowbuf[wv][cB & 1023], wB);
    LGKM0();
    #pragma unroll
    for (int i = 0; i < 4; ++i) {
      f32x4 val = ((const f32x4*)rowbuf[wv])[i * 64 + lane];
      __builtin_nontemporal_store(val, ((f32x4*)(arow + (h << 10))) + i * 64 + lane);
    }
    LGKM0();   // rowbuf reads drained before next-half zeroing
  }
}

extern "C" void kernel_launch(void* const* d_in, const int* in_sizes, int n_in,
                              void* d_out, int out_size, void* d_ws, size_t ws_size,
                              hipStream_t stream) {
  const float* q = (const float*)d_in[0];
  const float* k = (const float*)d_in[1];
  const float* v = (const float*)d_in[2];
  const int* mask = (const int*)d_in[3];
  float* out = (float*)d_out;
  float* attn = out + (size_t)NBH * LSEQ * DDIM;

  const size_t qk_elems = (size_t)NBH * DDIM * LSEQ;        // 2M floats each
  const size_t qk_bytes = 2 * qk_elems * sizeof(float);     // 16 MiB
  const size_t mb_bytes = (size_t)LSEQ * (LSEQ / 64) * 8;   // 512 KiB
  const bool has_full = ws_size >= qk_bytes + mb_bytes;

  float* qT = (float*)d_ws;
  float* kT = qT + qk_elems;
  unsigned long long* mbits = (unsigned long long*)(kT + qk_elems);

  if (has_full) {
    prep_kernel<<<512 + (LSEQ * (LSEQ / 64)) / 4, 256, 0, stream>>>(
        q, k, qT, kT, mask, mbits);
    sort_emit_kernel<<<NBH * DDIM, SNTHR, 0, stream>>>(qT, kT, 1, attn);
    row_kernel<true><<<(NBH * LSEQ) / 2, 128, 0, stream>>>(attn, v, nullptr, mbits, out);
  } else {
    sort_emit_kernel<<<NBH * DDIM, SNTHR, 0, stream>>>(q, k, DDIM, attn);
    row_kernel<false><<<(NBH * LSEQ) / 2, 128, 0, stream>>>(attn, v, mask, nullptr, out);
  }
}

// Round 17
// 127.559 us; speedup vs baseline: 1.1462x; 1.0555x over previous
//
#include <hip/hip_runtime.h>
#include <hip/hip_fp16.h>

// Problem: B=2, H=8, L=2048, D=64.
// out0 = masked(p + p^T) @ v   (B,H,L,D)
// out1 = p + p^T               (B,H,L,L)
// p[b,h,qi,ki] += exp(-(q_sorted_r - k_sorted_r)^2)/D for rank-matched sorted
// q/k along L per (b,h,d). Each attn row receives exactly 64 direct + 64
// transpose entries (one per d) -> collision-free 4B slot per entry in the
// first 512B of each row's dense output region (u16 col | fp16 weight).
//
// R17 = R16 (best: 134.6us) + (a) mask bit-pack merged into the sort_emit
// launch (tail-fill, removes a serialized prep slice), (b) v converted to
// fp16 in prep -> row gather traffic halves (128B/wave/entry, contiguous),
// (c) __expf in emit.

#define LSEQ 2048
#define DDIM 64
#define NBH  16
#define SNTHR 512
#define EPT  8   // elements per thread (per half) in sort
#define NPACKB 8192   // mask-pack blocks appended to sort grid (8 words each)

typedef float    f32x4 __attribute__((ext_vector_type(4)));
typedef unsigned u32x2 __attribute__((ext_vector_type(2)));

#define LGKM0() asm volatile("s_waitcnt lgkmcnt(0)" ::: "memory")

__device__ __forceinline__ unsigned long long pack_kv(float f, unsigned idx) {
  unsigned u = __float_as_uint(f);
  u = (u & 0x80000000u) ? ~u : (u | 0x80000000u);   // sortable-ascending
  return ((unsigned long long)u << 32) | idx;
}

__device__ __forceinline__ float unpack_val(unsigned long long p) {
  unsigned us = (unsigned)(p >> 32);
  unsigned u = (us & 0x80000000u) ? (us & 0x7fffffffu) : ~us;
  return __uint_as_float(u);
}

// lane-xor-1 / lane-xor-2 exchange via DPP quad_perm (VALU, no DS pipe).
template<int CTRL>
__device__ __forceinline__ unsigned long long dpp_swap(unsigned long long x) {
  int lo = __builtin_amdgcn_update_dpp(0, (int)(unsigned)x,         CTRL, 0xF, 0xF, true);
  int hi = __builtin_amdgcn_update_dpp(0, (int)(unsigned)(x >> 32), CTRL, 0xF, 0xF, true);
  return ((unsigned long long)(unsigned)hi << 32) | (unsigned)lo;
}

// ---- prep: blocks [0,512) transpose q,k -> [bh][D][L];
//      blocks [512, 512+1024) convert v f32 -> fp16 (2048 elems each)
__global__ __launch_bounds__(256) void prep_kernel(
    const float* __restrict__ q, const float* __restrict__ k,
    float* __restrict__ qT, float* __restrict__ kT,
    const float* __restrict__ v, __half* __restrict__ v16) {
  const int t = threadIdx.x;
  if (blockIdx.x < 512) {
    __shared__ float tq[64][65], tk[64][65];
    const int bh = blockIdx.x >> 5, chunk = blockIdx.x & 31;
    const size_t ib = (size_t)bh * LSEQ * DDIM + (size_t)chunk * 64 * DDIM;
    #pragma unroll
    for (int s = 0; s < 16; ++s) {
      int i = t + s * 256;              // 64(l) x 64(d) tile
      int l = i >> 6, d = i & 63;
      tq[l][d] = q[ib + i];
      tk[l][d] = k[ib + i];
    }
    __syncthreads();
    const size_t ob = (size_t)bh * DDIM * LSEQ + (size_t)chunk * 64;
    #pragma unroll
    for (int s = 0; s < 16; ++s) {
      int o = t + s * 256;
      int d = o >> 6, l = o & 63;
      qT[ob + (size_t)d * LSEQ + l] = tq[l][d];
      kT[ob + (size_t)d * LSEQ + l] = tk[l][d];
    }
  } else {
    // v -> fp16: 2048 contiguous elems per block (8 per thread)
    const size_t base = (size_t)(blockIdx.x - 512) * 2048 + (size_t)t * 8;
    f32x4 a0 = *(const f32x4*)(v + base);
    f32x4 a1 = *(const f32x4*)(v + base + 4);
    __half h[8] = {__float2half(a0.x), __float2half(a0.y), __float2half(a0.z),
                   __float2half(a0.w), __float2half(a1.x), __float2half(a1.y),
                   __float2half(a1.z), __float2half(a1.w)};
    *(f32x4*)(v16 + base) = *(const f32x4*)h;   // 16B store of 8 halves
  }
}

#define CSWP(a, x, y, up) \
  { if ((a[x] > a[y]) == (up)) { auto _t = a[x]; a[x] = a[y]; a[y] = _t; } }

// full bitonic sort of 8 contiguous elems (base index 8*tt); u8 = dir for kk=8
__device__ __forceinline__ void sort8(unsigned long long* a, bool u8) {
  CSWP(a,0,1,true);  CSWP(a,2,3,false); CSWP(a,4,5,true);  CSWP(a,6,7,false);
  CSWP(a,0,2,true);  CSWP(a,1,3,true);  CSWP(a,4,6,false); CSWP(a,5,7,false);
  CSWP(a,0,1,true);  CSWP(a,2,3,true);  CSWP(a,4,5,false); CSWP(a,6,7,false);
  CSWP(a,0,4,u8); CSWP(a,1,5,u8); CSWP(a,2,6,u8); CSWP(a,3,7,u8);
  CSWP(a,0,2,u8); CSWP(a,1,3,u8); CSWP(a,4,6,u8); CSWP(a,5,7,u8);
  CSWP(a,0,1,u8); CSWP(a,2,3,u8); CSWP(a,4,5,u8); CSWP(a,6,7,u8);
}

// bitonic merge j=4,2,1 over 8 contiguous elems, uniform direction
__device__ __forceinline__ void merge8(unsigned long long* a, bool up) {
  CSWP(a,0,4,up); CSWP(a,1,5,up); CSWP(a,2,6,up); CSWP(a,3,7,up);
  CSWP(a,0,2,up); CSWP(a,1,3,up); CSWP(a,4,6,up); CSWP(a,5,7,up);
  CSWP(a,0,1,up); CSWP(a,2,3,up); CSWP(a,4,5,up); CSWP(a,6,7,up);
}

__device__ __forceinline__ unsigned long long bmin(unsigned long long a, unsigned long long b) {
  return a < b ? a : b;
}
__device__ __forceinline__ unsigned long long bmax(unsigned long long a, unsigned long long b) {
  return a > b ? a : b;
}

// Blocks [0, 1024): one 512-thr block per (b,h,d); threads 0-255 sort q,
// 256-511 sort k (identical 2048-elem network per half, tt = t & 255).
// Stages j<=4: in-register merge8. j=8,16: DPP quad_perm. j=32..256:
// __shfl_xor. j=512,1024: per-half 16KB LDS, one pass per stage.
// Emit: halves publish sorted keys in LDS; each half reads the other's
// rank-partner and issues its own entry type (8 scatter stores/thread).
// Blocks [1024, 1024+NPACKB): mask bit-pack (8 u64 words per block).
__global__ __launch_bounds__(SNTHR) void sort_emit_kernel(
    const float* __restrict__ qsrc, const float* __restrict__ ksrc,
    int stride, float* __restrict__ attn,
    const int* __restrict__ mask, unsigned long long* __restrict__ mbits) {
  const int bid = blockIdx.x;
  const int t = threadIdx.x;
  if (bid >= NBH * DDIM) {
    // ---- mask bit-pack tail-fill: word w = (bid-1024)*8 + wave
    const int w = (bid - NBH * DDIM) * 8 + (t >> 6);
    const int lane = t & 63;
    unsigned long long b = __ballot(mask[(size_t)w * 64 + lane] != 0);
    if (lane == 0) mbits[w] = b;
    return;
  }

  __shared__ unsigned long long sx[2][EPT][256];   // 32 KB
  const int lb  = (bid & 7) * (NBH * DDIM / 8) + (bid >> 3);  // XCD chunking
  const int bh = lb >> 6, d = lb & 63;
  const int half = t >> 8;          // 0 = q, 1 = k
  const int tt = t & 255;           // position within the half's network

  unsigned long long rr[EPT];
  if (stride == 1) {
    const float* sp = (half ? ksrc : qsrc) + ((size_t)bh * DDIM + d) * LSEQ;
    f32x4 a0 = ((const f32x4*)sp)[2*tt], a1 = ((const f32x4*)sp)[2*tt+1];
    float va[8] = {a0.x,a0.y,a0.z,a0.w,a1.x,a1.y,a1.z,a1.w};
    #pragma unroll
    for (int p = 0; p < 8; ++p) rr[p] = pack_kv(va[p], 8*tt + p);
  } else {
    const float* sp = half ? ksrc : qsrc;
    const size_t base = (size_t)bh * LSEQ * DDIM + d;
    #pragma unroll
    for (int p = 0; p < 8; ++p) {
      int l = 8*tt + p;
      rr[p] = pack_kv(sp[base + (size_t)l * DDIM], l);
    }
  }

  sort8(rr, (tt & 1) == 0);

  for (int kk = 16; kk <= LSEQ; kk <<= 1) {
    const bool up = (((8 * tt) & kk) == 0);
    // LDS stages: j >= 512; one pass, both halves exchange simultaneously.
    for (int j = kk >> 1; j >= 512; j >>= 1) {
      const int m = j >> 3;
      const int pt = tt ^ m;
      const bool ks = (((tt & m) == 0) == up);
      __syncthreads();
      #pragma unroll
      for (int p = 0; p < EPT; ++p) sx[half][p][tt] = rr[p];
      __syncthreads();
      #pragma unroll
      for (int p = 0; p < EPT; ++p) {
        unsigned long long a = sx[half][p][pt];
        rr[p] = ks ? bmin(rr[p], a) : bmax(rr[p], a);
      }
    }
    // shfl stages: 32 <= j <= 256 (m = j/8 in 4..32) on the DS pipe
    const int jstart = (kk >> 1) < 256 ? (kk >> 1) : 256;
    for (int j = jstart; j >= 32; j >>= 1) {
      const int m = j >> 3;
      const bool ks = (((tt & m) == 0) == up);
      #pragma unroll
      for (int p = 0; p < EPT; ++p) {
        unsigned long long a = __shfl_xor(rr[p], m);
        rr[p] = ks ? bmin(rr[p], a) : bmax(rr[p], a);
      }
    }
    // m=2 stage (j=16) via DPP quad_perm [2,3,0,1]
    if (kk >= 32) {
      const bool ks = (((tt & 2) == 0) == up);
      #pragma unroll
      for (int p = 0; p < EPT; ++p) {
        unsigned long long a = dpp_swap<0x4E>(rr[p]);
        rr[p] = ks ? bmin(rr[p], a) : bmax(rr[p], a);
      }
    }
    // m=1 stage (j=8) via DPP quad_perm [1,0,3,2]
    {
      const bool ks = (((tt & 1) == 0) == up);
      #pragma unroll
      for (int p = 0; p < EPT; ++p) {
        unsigned long long a = dpp_swap<0xB1>(rr[p]);
        rr[p] = ks ? bmin(rr[p], a) : bmax(rr[p], a);
      }
    }
    merge8(rr, up);
  }

  // publish sorted keys; each half reads the other's rank-partner and emits
  // its own entry type. entry = u16 col | fp16 weight. PLAIN stores (R10).
  __syncthreads();
  #pragma unroll
  for (int p = 0; p < EPT; ++p) sx[half][p][tt] = rr[p];
  __syncthreads();
  float* abh = attn + (size_t)bh * LSEQ * LSEQ;
  #pragma unroll
  for (int p = 0; p < EPT; ++p) {
    unsigned long long mine  = rr[p];
    unsigned long long other = sx[half ^ 1][p][tt];
    unsigned mi = (unsigned)(mine  & 0xffffffffu);
    unsigned oi = (unsigned)(other & 0xffffffffu);
    float mv = unpack_val(mine), ov = unpack_val(other);
    float diff = mv - ov;
    float w = __expf(-diff * diff) * (1.0f / (float)DDIM);
    unsigned hw = (unsigned)__half_as_ushort(__float2half(w));
    // half 0 (mine=q): direct entry, row qi, slot d.
    // half 1 (mine=k): transpose entry, row ki, slot 64+d.
    ((unsigned*)(abh + (size_t)mi * LSEQ))[(half << 6) + d] = oi | (hw << 16);
  }
}

__device__ __forceinline__ float half_bits_to_f32(unsigned bits) {
  return __half2float(__ushort_as_half((unsigned short)bits));
}

// One WAVE per attn row (128-thr blocks = 2 independent waves, NO
// __syncthreads -- all LDS state is per-wave, ordered by wave-local lgkmcnt).
// Phase order: entry load -> mask compaction -> matvec (loads only) -> out
// store -> densify + NT dense-row stores LAST.
// BITS path gathers v from the fp16 copy (halved L2 traffic).
template<bool BITS>
__global__ __launch_bounds__(128) void row_kernel(
    float* __restrict__ attn, const float* __restrict__ v,
    const __half* __restrict__ v16,
    const int* __restrict__ mask, const unsigned long long* __restrict__ mbits,
    float* __restrict__ out) {
  __shared__ float rowbuf[2][1024];
  __shared__ unsigned cent[2][136];              // compacted active entries
  __shared__ unsigned long long mb[2][32];
  const int wv = threadIdx.x >> 6, lane = threadIdx.x & 63;
  const int bid = blockIdx.x;
  const int lb = (bid & 7) * ((NBH * LSEQ / 2) / 8) + (bid >> 3);  // XCD chunking
  const int R = lb * 2 + wv;
  const int bh = R >> 11, r = R & (LSEQ - 1);
  float* arow = attn + (size_t)R * LSEQ;

  // phase 1: loads. Entry list = first 512B of this row's dense region.
  u32x2 ep = __builtin_nontemporal_load(((const u32x2*)arow) + lane);
  if (BITS && lane < 32) mb[wv][lane] = mbits[(size_t)r * 32 + lane];

  // phase 2: active tests + ballot compaction (lane holds entries 2l, 2l+1)
  const unsigned cA = ep.x & 0xFFFFu, cB = ep.y & 0xFFFFu;
  bool aA, aB;
  if (BITS) {
    LGKM0();
    aA = !((mb[wv][cA >> 6] >> (cA & 63)) & 1ull);
    aB = !((mb[wv][cB >> 6] >> (cB & 63)) & 1ull);
  } else {
    const int* mrow = mask + (size_t)r * LSEQ;
    aA = (mrow[cA] == 0);
    aB = (mrow[cB] == 0);
  }
  unsigned long long m0 = __ballot(aA), m1 = __ballot(aB);
  int n0 = __popcll(m0);
  int n  = n0 + __popcll(m1);
  if (aA) cent[wv][__popcll(m0 & ((1ull << lane) - 1ull))] = ep.x;
  if (aB) cent[wv][n0 + __popcll(m1 & ((1ull << lane) - 1ull))] = ep.y;
  int npad = (n + 7) & ~7;
  if (lane < npad - n) cent[wv][n + lane] = 0u;   // col 0, w = 0
  LGKM0();

  // phase 3: matvec over active entries only (pure loads, 8 accumulators)
  float acc[8];
  #pragma unroll
  for (int u = 0; u < 8; ++u) acc[u] = 0.0f;
  if (BITS) {
    const __half* vb = v16 + (size_t)bh * LSEQ * DDIM;
    for (int e = 0; e < npad; e += 8) {
      #pragma unroll
      for (int u = 0; u < 8; ++u) {
        unsigned en = cent[wv][e + u];
        acc[u] += half_bits_to_f32(en >> 16) *
                  __half2float(vb[(size_t)(en & 0xFFFFu) * DDIM + lane]);
      }
    }
  } else {
    const float* vb = v + (size_t)bh * LSEQ * DDIM;
    for (int e = 0; e < npad; e += 8) {
      #pragma unroll
      for (int u = 0; u < 8; ++u) {
        unsigned en = cent[wv][e + u];
        acc[u] += half_bits_to_f32(en >> 16) *
                  vb[(size_t)(en & 0xFFFFu) * DDIM + lane];
      }
    }
  }
  float s = ((acc[0] + acc[1]) + (acc[2] + acc[3])) +
            ((acc[4] + acc[5]) + (acc[6] + acc[7]));
  out[(size_t)R * DDIM + lane] = s;

  // phase 4: densify + dense-row NT stores (LAST; nothing waits on them)
  const float wA = half_bits_to_f32(ep.x >> 16);
  const float wB = half_bits_to_f32(ep.y >> 16);
  #pragma unroll
  for (int h = 0; h < 2; ++h) {
    f32x4 z = {0.0f, 0.0f, 0.0f, 0.0f};
    #pragma unroll
    for (int i = 0; i < 4; ++i) ((f32x4*)rowbuf[wv])[i * 64 + lane] = z;
    LGKM0();
    if ((int)(cA >> 10) == h) atomicAdd(&rowbuf[wv][cA & 1023], wA);
    if ((int)(cB >> 10) == h) atomicAdd(&rowbuf[wv][cB & 1023], wB);
    LGKM0();
    #pragma unroll
    for (int i = 0; i < 4; ++i) {
      f32x4 val = ((const f32x4*)rowbuf[wv])[i * 64 + lane];
      __builtin_nontemporal_store(val, ((f32x4*)(arow + (h << 10))) + i * 64 + lane);
    }
    LGKM0();   // rowbuf reads drained before next-half zeroing
  }
}

extern "C" void kernel_launch(void* const* d_in, const int* in_sizes, int n_in,
                              void* d_out, int out_size, void* d_ws, size_t ws_size,
                              hipStream_t stream) {
  const float* q = (const float*)d_in[0];
  const float* k = (const float*)d_in[1];
  const float* v = (const float*)d_in[2];
  const int* mask = (const int*)d_in[3];
  float* out = (float*)d_out;
  float* attn = out + (size_t)NBH * LSEQ * DDIM;

  const size_t qk_elems = (size_t)NBH * DDIM * LSEQ;        // 2M floats each
  const size_t qk_bytes = 2 * qk_elems * sizeof(float);     // 16 MiB
  const size_t mb_bytes = (size_t)LSEQ * (LSEQ / 64) * 8;   // 512 KiB
  const size_t v16_bytes = qk_elems * sizeof(__half);       // 4 MiB
  const bool has_full = ws_size >= qk_bytes + mb_bytes + v16_bytes;

  float* qT = (float*)d_ws;
  float* kT = qT + qk_elems;
  unsigned long long* mbits = (unsigned long long*)(kT + qk_elems);
  __half* v16 = (__half*)(mbits + LSEQ * (LSEQ / 64));

  if (has_full) {
    prep_kernel<<<512 + 1024, 256, 0, stream>>>(q, k, qT, kT, v, v16);
    sort_emit_kernel<<<NBH * DDIM + NPACKB, SNTHR, 0, stream>>>(
        qT, kT, 1, attn, mask, mbits);
    row_kernel<true><<<(NBH * LSEQ) / 2, 128, 0, stream>>>(
        attn, v, v16, nullptr, mbits, out);
  } else {
    sort_emit_kernel<<<NBH * DDIM, SNTHR, 0, stream>>>(
        q, k, DDIM, attn, mask, nullptr);
    row_kernel<false><<<(NBH * LSEQ) / 2, 128, 0, stream>>>(
        attn, v, nullptr, mask, nullptr, out);
  }
}